// Round 1
// baseline (4835.051 us; speedup 1.0000x reference)
//
#include <hip/hip_runtime.h>
#include <math.h>

#define B_   256
#define H_   512
#define V_   16000
#define M_   32
#define G3_  1536      // 3*H
#define SOS_ 1
#define EOS_ 2

// ---------------------------------------------------------------------------
// init: h0 = h1 = sem_f ; inputs = SOS ; finished = 0
// ---------------------------------------------------------------------------
__global__ __launch_bounds__(256)
void init_kernel(const float* __restrict__ sem_f,
                 float* __restrict__ h0, float* __restrict__ h1,
                 int* __restrict__ inputs, int* __restrict__ finished)
{
    int i = blockIdx.x * 256 + threadIdx.x;
    if (i < B_ * H_) {
        float v = sem_f[i];
        h0[i] = v;
        h1[i] = v;
    }
    if (i < B_) {
        inputs[i] = SOS_;
        finished[i] = 0;
    }
}

// ---------------------------------------------------------------------------
// GRU pre-activation GEMM:
//   PRE[b, 0:1536]    = x @ W_ih^T + b_ih      (x = emb[inputs[b]] if GATHER)
//   PRE[b, 1536:3072] = h @ W_hh^T + b_hh
// grid (24, 4): blockIdx.x = 128-col tile over 3072, blockIdx.y = 64-row tile
// block 256 threads, each computes 4 rows x 8 cols, BK = 32.
// ---------------------------------------------------------------------------
template<bool GATHER>
__global__ __launch_bounds__(256)
void gru_gemm(const float* __restrict__ x,       // [B,H]  (used if !GATHER)
              const float* __restrict__ emb,     // [V,H]  (used if GATHER)
              const int*   __restrict__ inputs,  // [B]
              const float* __restrict__ h,       // [B,H]
              const float* __restrict__ W_ih,    // [1536,512]
              const float* __restrict__ W_hh,    // [1536,512]
              const float* __restrict__ b_ih,    // [1536]
              const float* __restrict__ b_hh,    // [1536]
              float* __restrict__ PRE)           // [B,3072]
{
    const int ct = blockIdx.x;          // 0..23
    const int rt = blockIdx.y;          // 0..3
    const bool is_ih = (ct < 12);
    const int wrow0 = (is_ih ? ct : ct - 12) * 128;  // row offset in W / bias
    const int row0  = rt * 64;

    const float* W    = is_ih ? W_ih : W_hh;
    const float* bias = is_ih ? b_ih : b_hh;

    __shared__ float As[32][64];    // [k][row]
    __shared__ float Ws[32][128];   // [k][col]

    const int tid   = threadIdx.x;
    const int row_g = tid & 15;     // 16 groups of 4 rows
    const int col_g = tid >> 4;     // 16 groups of 8 cols

    float acc[4][8];
#pragma unroll
    for (int i = 0; i < 4; ++i)
#pragma unroll
        for (int j = 0; j < 8; ++j) acc[i][j] = 0.f;

    // staging assignments
    const int ar  = tid >> 2;       // 0..63 : A row within tile
    const int akq = tid & 3;        // 0..3  : 8-float k chunk
    const float* aptr;
    if (GATHER) {
        if (is_ih) aptr = emb + (size_t)inputs[row0 + ar] * H_;
        else       aptr = h   + (size_t)(row0 + ar) * H_;
    } else {
        aptr = (is_ih ? x : h) + (size_t)(row0 + ar) * H_;
    }
    const int wc  = tid >> 1;       // 0..127 : W row within tile
    const int wkq = (tid & 1) * 16; // 0 or 16
    const float* wptr = W + (size_t)(wrow0 + wc) * H_;

    for (int k0 = 0; k0 < H_; k0 += 32) {
        float4 a0 = *(const float4*)(aptr + k0 + akq * 8);
        float4 a1 = *(const float4*)(aptr + k0 + akq * 8 + 4);
        float4 w0 = *(const float4*)(wptr + k0 + wkq);
        float4 w1 = *(const float4*)(wptr + k0 + wkq + 4);
        float4 w2 = *(const float4*)(wptr + k0 + wkq + 8);
        float4 w3 = *(const float4*)(wptr + k0 + wkq + 12);
        __syncthreads();            // previous iteration's reads done
        As[akq*8+0][ar] = a0.x; As[akq*8+1][ar] = a0.y;
        As[akq*8+2][ar] = a0.z; As[akq*8+3][ar] = a0.w;
        As[akq*8+4][ar] = a1.x; As[akq*8+5][ar] = a1.y;
        As[akq*8+6][ar] = a1.z; As[akq*8+7][ar] = a1.w;
        Ws[wkq+ 0][wc] = w0.x; Ws[wkq+ 1][wc] = w0.y;
        Ws[wkq+ 2][wc] = w0.z; Ws[wkq+ 3][wc] = w0.w;
        Ws[wkq+ 4][wc] = w1.x; Ws[wkq+ 5][wc] = w1.y;
        Ws[wkq+ 6][wc] = w1.z; Ws[wkq+ 7][wc] = w1.w;
        Ws[wkq+ 8][wc] = w2.x; Ws[wkq+ 9][wc] = w2.y;
        Ws[wkq+10][wc] = w2.z; Ws[wkq+11][wc] = w2.w;
        Ws[wkq+12][wc] = w3.x; Ws[wkq+13][wc] = w3.y;
        Ws[wkq+14][wc] = w3.z; Ws[wkq+15][wc] = w3.w;
        __syncthreads();
#pragma unroll
        for (int k = 0; k < 32; ++k) {
            const float4 a  = *(const float4*)&As[k][row_g * 4];
            const float4 wA = *(const float4*)&Ws[k][col_g * 8];
            const float4 wB = *(const float4*)&Ws[k][col_g * 8 + 4];
            const float av[4] = {a.x, a.y, a.z, a.w};
            const float wv[8] = {wA.x, wA.y, wA.z, wA.w, wB.x, wB.y, wB.z, wB.w};
#pragma unroll
            for (int i = 0; i < 4; ++i)
#pragma unroll
                for (int j = 0; j < 8; ++j)
                    acc[i][j] = fmaf(av[i], wv[j], acc[i][j]);
        }
    }

    // epilogue: add bias, store PRE
    const int ocol = ct * 128 + col_g * 8;        // 0..3071
    const int bcol = wrow0 + col_g * 8;           // 0..1535 (bias index)
#pragma unroll
    for (int i = 0; i < 4; ++i) {
        const int r = row0 + row_g * 4 + i;
        float o[8];
#pragma unroll
        for (int j = 0; j < 8; ++j) o[j] = acc[i][j] + bias[bcol + j];
        float* dst = PRE + (size_t)r * 3072 + ocol;
        *(float4*)(dst)     = make_float4(o[0], o[1], o[2], o[3]);
        *(float4*)(dst + 4) = make_float4(o[4], o[5], o[6], o[7]);
    }
}

// ---------------------------------------------------------------------------
// GRU gate math (elementwise). In-place update of h with freeze.
// ---------------------------------------------------------------------------
__global__ __launch_bounds__(256)
void gate_kernel(const float* __restrict__ PRE,
                 float* __restrict__ h,
                 const int* __restrict__ finished)
{
    const int idx = blockIdx.x * 256 + threadIdx.x;   // [0, B*H)
    const int b = idx >> 9;
    const int j = idx & 511;
    if (finished[b]) return;                           // frozen row
    const float* p = PRE + (size_t)b * 3072;
    const float ir = p[j],        iz = p[512 + j],  in_ = p[1024 + j];
    const float hr = p[1536 + j], hz = p[2048 + j], hn  = p[2560 + j];
    const float r = 1.0f / (1.0f + expf(-(ir + hr)));
    const float z = 1.0f / (1.0f + expf(-(iz + hz)));
    const float n = tanhf(in_ + r * hn);
    const float hv = h[idx];
    h[idx] = (1.0f - z) * n + z * hv;
}

// ---------------------------------------------------------------------------
// FC GEMM + logits store + per-(row, col-tile) argmax partials.
// grid (125, 4): col tile 128 over 16000, row tile 64.
// ---------------------------------------------------------------------------
__global__ __launch_bounds__(256)
void fc_gemm(const float* __restrict__ h1,     // [B,H]
             const float* __restrict__ fcW,    // [V,H]
             const float* __restrict__ fcb,    // [V]
             const int*   __restrict__ finished,
             float* __restrict__ logits,       // [B,M,V] base
             float* __restrict__ pmax,         // [B,128]
             int*   __restrict__ pidx,         // [B,128]
             int t)
{
    const int ct = blockIdx.x;      // 0..124
    const int rt = blockIdx.y;      // 0..3
    const int col0 = ct * 128;
    const int row0 = rt * 64;

    __shared__ float As[32][64];
    __shared__ float Ws[32][128];
    __shared__ float pm[16][64];
    __shared__ int   pix[16][64];

    const int tid   = threadIdx.x;
    const int row_g = tid & 15;
    const int col_g = tid >> 4;

    float acc[4][8];
#pragma unroll
    for (int i = 0; i < 4; ++i)
#pragma unroll
        for (int j = 0; j < 8; ++j) acc[i][j] = 0.f;

    const int ar  = tid >> 2;
    const int akq = tid & 3;
    const float* aptr = h1 + (size_t)(row0 + ar) * H_;
    const int wc  = tid >> 1;
    const int wkq = (tid & 1) * 16;
    const float* wptr = fcW + (size_t)(col0 + wc) * H_;

    for (int k0 = 0; k0 < H_; k0 += 32) {
        float4 a0 = *(const float4*)(aptr + k0 + akq * 8);
        float4 a1 = *(const float4*)(aptr + k0 + akq * 8 + 4);
        float4 w0 = *(const float4*)(wptr + k0 + wkq);
        float4 w1 = *(const float4*)(wptr + k0 + wkq + 4);
        float4 w2 = *(const float4*)(wptr + k0 + wkq + 8);
        float4 w3 = *(const float4*)(wptr + k0 + wkq + 12);
        __syncthreads();
        As[akq*8+0][ar] = a0.x; As[akq*8+1][ar] = a0.y;
        As[akq*8+2][ar] = a0.z; As[akq*8+3][ar] = a0.w;
        As[akq*8+4][ar] = a1.x; As[akq*8+5][ar] = a1.y;
        As[akq*8+6][ar] = a1.z; As[akq*8+7][ar] = a1.w;
        Ws[wkq+ 0][wc] = w0.x; Ws[wkq+ 1][wc] = w0.y;
        Ws[wkq+ 2][wc] = w0.z; Ws[wkq+ 3][wc] = w0.w;
        Ws[wkq+ 4][wc] = w1.x; Ws[wkq+ 5][wc] = w1.y;
        Ws[wkq+ 6][wc] = w1.z; Ws[wkq+ 7][wc] = w1.w;
        Ws[wkq+ 8][wc] = w2.x; Ws[wkq+ 9][wc] = w2.y;
        Ws[wkq+10][wc] = w2.z; Ws[wkq+11][wc] = w2.w;
        Ws[wkq+12][wc] = w3.x; Ws[wkq+13][wc] = w3.y;
        Ws[wkq+14][wc] = w3.z; Ws[wkq+15][wc] = w3.w;
        __syncthreads();
#pragma unroll
        for (int k = 0; k < 32; ++k) {
            const float4 a  = *(const float4*)&As[k][row_g * 4];
            const float4 wA = *(const float4*)&Ws[k][col_g * 8];
            const float4 wB = *(const float4*)&Ws[k][col_g * 8 + 4];
            const float av[4] = {a.x, a.y, a.z, a.w};
            const float wv[8] = {wA.x, wA.y, wA.z, wA.w, wB.x, wB.y, wB.z, wB.w};
#pragma unroll
            for (int i = 0; i < 4; ++i)
#pragma unroll
                for (int j = 0; j < 8; ++j)
                    acc[i][j] = fmaf(av[i], wv[j], acc[i][j]);
        }
    }

    // epilogue: bias, logits store (0 for finished rows), local argmax
    const int cbase = col0 + col_g * 8;
#pragma unroll
    for (int i = 0; i < 4; ++i) {
        const int b  = row0 + row_g * 4 + i;
        const int fin = finished[b];
        float o[8];
        float bv = -INFINITY; int bi = 0;
#pragma unroll
        for (int j = 0; j < 8; ++j) {
            o[j] = acc[i][j] + fcb[cbase + j];
            if (o[j] > bv) { bv = o[j]; bi = cbase + j; }   // first-max wins
        }
        float* dst = logits + (size_t)b * (M_ * (size_t)V_) + (size_t)t * V_ + cbase;
        if (fin) {
            *(float4*)(dst)     = make_float4(0.f, 0.f, 0.f, 0.f);
            *(float4*)(dst + 4) = make_float4(0.f, 0.f, 0.f, 0.f);
        } else {
            *(float4*)(dst)     = make_float4(o[0], o[1], o[2], o[3]);
            *(float4*)(dst + 4) = make_float4(o[4], o[5], o[6], o[7]);
        }
        pm [col_g][row_g * 4 + i] = bv;
        pix[col_g][row_g * 4 + i] = bi;
    }
    __syncthreads();
    if (tid < 64) {
        float bv = pm[0][tid]; int bi = pix[0][tid];
#pragma unroll
        for (int cg = 1; cg < 16; ++cg) {
            const float v = pm[cg][tid];
            if (v > bv) { bv = v; bi = pix[cg][tid]; }      // ascending col order
        }
        const int b = row0 + tid;
        pmax[b * 128 + ct] = bv;
        pidx[b * 128 + ct] = bi;
    }
}

// ---------------------------------------------------------------------------
// finalize: reduce 125 argmax partials per row, write decoded/mask,
// update inputs/finished.
// ---------------------------------------------------------------------------
__global__ __launch_bounds__(128)
void finalize_kernel(const float* __restrict__ pmax, const int* __restrict__ pidx,
                     int* __restrict__ inputs, int* __restrict__ finished,
                     float* __restrict__ decoded_out, float* __restrict__ mask_out,
                     int t)
{
    const int b = blockIdx.x;
    const int tid = threadIdx.x;
    __shared__ float sv[128];
    __shared__ int   si[128];
    float v = -INFINITY; int ix = 0x7fffffff;
    if (tid < 125) { v = pmax[b * 128 + tid]; ix = pidx[b * 128 + tid]; }
    sv[tid] = v; si[tid] = ix;
    __syncthreads();
    for (int s = 64; s > 0; s >>= 1) {
        if (tid < s) {
            const float v2 = sv[tid + s]; const int i2 = si[tid + s];
            if (v2 > sv[tid] || (v2 == sv[tid] && i2 < si[tid])) {
                sv[tid] = v2; si[tid] = i2;
            }
        }
        __syncthreads();
    }
    if (tid == 0) {
        const int fin = finished[b];
        const int dec = si[0];
        decoded_out[b * M_ + t] = fin ? -1.0f : (float)dec;
        mask_out   [b * M_ + t] = fin ? 0.0f : 1.0f;
        if (!fin) {
            inputs[b] = dec;
            if (dec == EOS_) finished[b] = 1;
        }
    }
}

// ---------------------------------------------------------------------------
extern "C" void kernel_launch(void* const* d_in, const int* in_sizes, int n_in,
                              void* d_out, int out_size, void* d_ws, size_t ws_size,
                              hipStream_t stream)
{
    const float* sem_f = (const float*)d_in[0];
    const float* emb   = (const float*)d_in[1];
    const float* W_ih0 = (const float*)d_in[2];
    const float* W_hh0 = (const float*)d_in[3];
    const float* b_ih0 = (const float*)d_in[4];
    const float* b_hh0 = (const float*)d_in[5];
    const float* W_ih1 = (const float*)d_in[6];
    const float* W_hh1 = (const float*)d_in[7];
    const float* b_ih1 = (const float*)d_in[8];
    const float* b_hh1 = (const float*)d_in[9];
    const float* fc_W  = (const float*)d_in[10];
    const float* fc_b  = (const float*)d_in[11];

    float* out = (float*)d_out;
    float* decoded_out = out;                                       // [B,M]
    float* logits_out  = out + (size_t)B_ * M_;                     // [B,M,V]
    float* mask_out    = out + (size_t)B_ * M_ + (size_t)B_ * M_ * V_; // [B,M]

    // workspace carve (floats)
    float* ws = (float*)d_ws;
    float* h0   = ws;                       // 131072
    float* h1   = ws + 131072;              // 131072
    float* PRE  = ws + 262144;              // 256*3072 = 786432
    float* pmax = ws + 1048576;             // 256*128  = 32768
    int*   pidx     = (int*)(ws + 1081344); // 32768
    int*   inputs   = (int*)(ws + 1114112); // 256
    int*   finished = (int*)(ws + 1114368); // 256

    init_kernel<<<(B_ * H_ + 255) / 256, 256, 0, stream>>>(sem_f, h0, h1, inputs, finished);

    const dim3 gruGrid(24, 4);
    const dim3 fcGrid(125, 4);

    for (int t = 0; t < M_; ++t) {
        gru_gemm<true><<<gruGrid, 256, 0, stream>>>(
            nullptr, emb, inputs, h0, W_ih0, W_hh0, b_ih0, b_hh0, PRE);
        gate_kernel<<<(B_ * H_) / 256, 256, 0, stream>>>(PRE, h0, finished);
        gru_gemm<false><<<gruGrid, 256, 0, stream>>>(
            h0, nullptr, nullptr, h1, W_ih1, W_hh1, b_ih1, b_hh1, PRE);
        gate_kernel<<<(B_ * H_) / 256, 256, 0, stream>>>(PRE, h1, finished);
        fc_gemm<<<fcGrid, 256, 0, stream>>>(
            h1, fc_W, fc_b, finished, logits_out, pmax, pidx, t);
        finalize_kernel<<<B_, 128, 0, stream>>>(
            pmax, pidx, inputs, finished, decoded_out, mask_out, t);
    }
}

// Round 2
// 3078.805 us; speedup vs baseline: 1.5704x; 1.5704x over previous
//
#include <hip/hip_runtime.h>
#include <math.h>

#define B_   256
#define H_   512
#define V_   16000
#define M_   32
#define SOS_ 1
#define EOS_ 2
#define INV_SCALE (1.0f/2048.0f)

typedef _Float16 half_t;
typedef _Float16 f16x8 __attribute__((ext_vector_type(8)));
typedef float    f32x4 __attribute__((ext_vector_type(4)));

__device__ __forceinline__ void split_f32(float x, half_t& a, half_t& b) {
    a = (half_t)x;
    b = (half_t)((x - (float)a) * 2048.0f);
}

// ---------------------------------------------------------------------------
// init: h0 = h1 = sem_f (+ fp16x2 splits); x = emb[SOS] split; inputs; finished
// ---------------------------------------------------------------------------
__global__ __launch_bounds__(256)
void init_kernel(const float* __restrict__ sem_f, const float* __restrict__ emb,
                 float* __restrict__ h0, float* __restrict__ h1,
                 half_t* __restrict__ h0a, half_t* __restrict__ h0b,
                 half_t* __restrict__ h1a, half_t* __restrict__ h1b,
                 half_t* __restrict__ xa,  half_t* __restrict__ xb,
                 int* __restrict__ inputs, int* __restrict__ finished)
{
    const int i = blockIdx.x * 256 + threadIdx.x;
    if (i < B_ * H_) {
        const float v = sem_f[i];
        h0[i] = v; h1[i] = v;
        half_t a, b; split_f32(v, a, b);
        h0a[i] = a; h0b[i] = b;
        h1a[i] = a; h1b[i] = b;
        const int j = i & (H_ - 1);
        const float xv = emb[SOS_ * H_ + j];
        half_t c, d; split_f32(xv, c, d);
        xa[i] = c; xb[i] = d;
    }
    if (i < B_) { inputs[i] = SOS_; finished[i] = 0; }
}

// ---------------------------------------------------------------------------
// GRU pre-activation GEMM via fp16x2 MFMA (3-pass).
//   PRE[b, 0:1536]    = Ai @ W_ih^T + (bias in epilogue)
//   PRE[b, 1536:3072] = Ah @ W_hh^T
// grid (24, 8): ct = 128-col tile over 3072, rt = 32-row tile.
// block 256 = 4 waves; wave w: rows 0..31 (rf=2), cols 32w..32w+31 (cf=2).
// A fragments read directly from global pre-split fp16 planes.
// ---------------------------------------------------------------------------
__global__ __launch_bounds__(256)
void gru_gemm_mfma(const half_t* __restrict__ Aia, const half_t* __restrict__ Aib,
                   const half_t* __restrict__ Aha, const half_t* __restrict__ Ahb,
                   const float* __restrict__ W_ih, const float* __restrict__ W_hh,
                   const float* __restrict__ b_ih, const float* __restrict__ b_hh,
                   float* __restrict__ PRE)
{
    const int ct = blockIdx.x;            // 0..23
    const int rt = blockIdx.y;            // 0..7
    const bool is_ih = (ct < 12);
    const int wrow0 = (is_ih ? ct : ct - 12) * 128;
    const int row0  = rt * 32;
    const float* W    = is_ih ? W_ih : W_hh;
    const float* bias = is_ih ? b_ih : b_hh;
    const half_t* Aa  = is_ih ? Aia : Aha;
    const half_t* Ab  = is_ih ? Aib : Ahb;

    __shared__ half_t W0s[128][40];       // stride 40 halves (80B): 2-way-free banks
    __shared__ half_t W1s[128][40];

    const int tid  = threadIdx.x;
    const int w    = tid >> 6;            // wave 0..3
    const int lane = tid & 63;
    const int ll   = lane & 15;
    const int lg   = lane >> 4;           // 0..3

    const int sc = tid >> 1;              // staged W row (0..127)
    const int sk = (tid & 1) * 16;        // k chunk 0 / 16
    const float* wp = W + (size_t)(wrow0 + sc) * H_ + sk;

    f32x4 accM[2][2] = {};                // [rf][cf] main (x0*y0)
    f32x4 accC[2][2] = {};                // cross (x0*y1s + x1s*y0)

    for (int k0 = 0; k0 < H_; k0 += 32) {
        const float4 q0 = *(const float4*)(wp + k0);
        const float4 q1 = *(const float4*)(wp + k0 + 4);
        const float4 q2 = *(const float4*)(wp + k0 + 8);
        const float4 q3 = *(const float4*)(wp + k0 + 12);
        const float tmp[16] = {q0.x,q0.y,q0.z,q0.w, q1.x,q1.y,q1.z,q1.w,
                               q2.x,q2.y,q2.z,q2.w, q3.x,q3.y,q3.z,q3.w};
        f16x8 p0a, p0b, p1a, p1b;
#pragma unroll
        for (int i = 0; i < 8; ++i) { half_t a,b; split_f32(tmp[i],   a,b); p0a[i]=a; p1a[i]=b; }
#pragma unroll
        for (int i = 0; i < 8; ++i) { half_t a,b; split_f32(tmp[8+i], a,b); p0b[i]=a; p1b[i]=b; }
        __syncthreads();                  // previous iteration's LDS reads done
        *(f16x8*)&W0s[sc][sk]     = p0a;
        *(f16x8*)&W0s[sc][sk + 8] = p0b;
        *(f16x8*)&W1s[sc][sk]     = p1a;
        *(f16x8*)&W1s[sc][sk + 8] = p1b;
        __syncthreads();

        f16x8 a0[2], a1[2];
#pragma unroll
        for (int rf = 0; rf < 2; ++rf) {
            const size_t off = ((size_t)(row0 + 16*rf + ll) << 9) + k0 + (lg << 3);
            a0[rf] = *(const f16x8*)(Aa + off);
            a1[rf] = *(const f16x8*)(Ab + off);
        }
#pragma unroll
        for (int cf = 0; cf < 2; ++cf) {
            const int c = 32*w + 16*cf + ll;
            const f16x8 b0 = *(const f16x8*)&W0s[c][lg << 3];
            const f16x8 b1 = *(const f16x8*)&W1s[c][lg << 3];
#pragma unroll
            for (int rf = 0; rf < 2; ++rf) {
                accM[rf][cf] = __builtin_amdgcn_mfma_f32_16x16x32_f16(a0[rf], b0, accM[rf][cf], 0,0,0);
                accC[rf][cf] = __builtin_amdgcn_mfma_f32_16x16x32_f16(a0[rf], b1, accC[rf][cf], 0,0,0);
                accC[rf][cf] = __builtin_amdgcn_mfma_f32_16x16x32_f16(a1[rf], b0, accC[rf][cf], 0,0,0);
            }
        }
    }

    // epilogue: recombine, add bias, store PRE. C layout: col=lane&15, row=lg*4+reg.
#pragma unroll
    for (int cf = 0; cf < 2; ++cf) {
        const int cl = 32*w + 16*cf + ll;            // 0..127
        const float bv = bias[wrow0 + cl];
        const int c = ct * 128 + cl;
#pragma unroll
        for (int rf = 0; rf < 2; ++rf) {
#pragma unroll
            for (int r = 0; r < 4; ++r) {
                const int row = row0 + 16*rf + lg*4 + r;
                PRE[(size_t)row * 3072 + c] = accM[rf][cf][r] + accC[rf][cf][r] * INV_SCALE + bv;
            }
        }
    }
}

// ---------------------------------------------------------------------------
// GRU gate math; in-place h update with freeze + fp16x2 split emit.
// ---------------------------------------------------------------------------
__global__ __launch_bounds__(256)
void gate_kernel(const float* __restrict__ PRE,
                 float* __restrict__ h,
                 half_t* __restrict__ ha, half_t* __restrict__ hb,
                 const int* __restrict__ finished)
{
    const int idx = blockIdx.x * 256 + threadIdx.x;
    const int b = idx >> 9;
    const int j = idx & 511;
    if (finished[b]) return;                 // frozen: h and its split stay valid
    const float* p = PRE + (size_t)b * 3072;
    const float ir = p[j],        iz = p[512 + j],  in_ = p[1024 + j];
    const float hr = p[1536 + j], hz = p[2048 + j], hn  = p[2560 + j];
    const float r = 1.0f / (1.0f + expf(-(ir + hr)));
    const float z = 1.0f / (1.0f + expf(-(iz + hz)));
    const float n = tanhf(in_ + r * hn);
    const float hv = (1.0f - z) * n + z * h[idx];
    h[idx] = hv;
    half_t a, bb; split_f32(hv, a, bb);
    ha[idx] = a; hb[idx] = bb;
}

// ---------------------------------------------------------------------------
// FC GEMM via fp16x2 MFMA: logits = h1 @ fc_W^T + fc_b, zeroed for finished.
// grid (125, 4): 128-col x 64-row tiles; 4 waves (2x2), wave = 32 rows x 64 cols.
// ---------------------------------------------------------------------------
__global__ __launch_bounds__(256)
void fc_gemm_mfma(const half_t* __restrict__ Aa, const half_t* __restrict__ Ab,
                  const float* __restrict__ fcW, const float* __restrict__ fcb,
                  const int* __restrict__ finished,
                  float* __restrict__ logits, int t)
{
    const int ct = blockIdx.x;            // 0..124
    const int rt = blockIdx.y;            // 0..3
    const int col0 = ct * 128;
    const int row0 = rt * 64;

    __shared__ half_t W0s[128][40];
    __shared__ half_t W1s[128][40];

    const int tid  = threadIdx.x;
    const int wv   = tid >> 6;
    const int wr   = wv >> 1, wc = wv & 1;
    const int lane = tid & 63;
    const int ll   = lane & 15, lg = lane >> 4;

    const int sc = tid >> 1;
    const int sk = (tid & 1) * 16;
    const float* wp = fcW + (size_t)(col0 + sc) * H_ + sk;

    f32x4 accM[2][4] = {};
    f32x4 accC[2][4] = {};

    for (int k0 = 0; k0 < H_; k0 += 32) {
        const float4 q0 = *(const float4*)(wp + k0);
        const float4 q1 = *(const float4*)(wp + k0 + 4);
        const float4 q2 = *(const float4*)(wp + k0 + 8);
        const float4 q3 = *(const float4*)(wp + k0 + 12);
        const float tmp[16] = {q0.x,q0.y,q0.z,q0.w, q1.x,q1.y,q1.z,q1.w,
                               q2.x,q2.y,q2.z,q2.w, q3.x,q3.y,q3.z,q3.w};
        f16x8 p0a, p0b, p1a, p1b;
#pragma unroll
        for (int i = 0; i < 8; ++i) { half_t a,b; split_f32(tmp[i],   a,b); p0a[i]=a; p1a[i]=b; }
#pragma unroll
        for (int i = 0; i < 8; ++i) { half_t a,b; split_f32(tmp[8+i], a,b); p0b[i]=a; p1b[i]=b; }
        __syncthreads();
        *(f16x8*)&W0s[sc][sk]     = p0a;
        *(f16x8*)&W0s[sc][sk + 8] = p0b;
        *(f16x8*)&W1s[sc][sk]     = p1a;
        *(f16x8*)&W1s[sc][sk + 8] = p1b;
        __syncthreads();

        f16x8 a0[2], a1[2];
#pragma unroll
        for (int rf = 0; rf < 2; ++rf) {
            const size_t off = ((size_t)(row0 + 32*wr + 16*rf + ll) << 9) + k0 + (lg << 3);
            a0[rf] = *(const f16x8*)(Aa + off);
            a1[rf] = *(const f16x8*)(Ab + off);
        }
#pragma unroll
        for (int cf = 0; cf < 4; ++cf) {
            const int c = 64*wc + 16*cf + ll;
            const f16x8 b0 = *(const f16x8*)&W0s[c][lg << 3];
            const f16x8 b1 = *(const f16x8*)&W1s[c][lg << 3];
#pragma unroll
            for (int rf = 0; rf < 2; ++rf) {
                accM[rf][cf] = __builtin_amdgcn_mfma_f32_16x16x32_f16(a0[rf], b0, accM[rf][cf], 0,0,0);
                accC[rf][cf] = __builtin_amdgcn_mfma_f32_16x16x32_f16(a0[rf], b1, accC[rf][cf], 0,0,0);
                accC[rf][cf] = __builtin_amdgcn_mfma_f32_16x16x32_f16(a1[rf], b0, accC[rf][cf], 0,0,0);
            }
        }
    }

    int fin[2][4];
#pragma unroll
    for (int rf = 0; rf < 2; ++rf)
#pragma unroll
        for (int r = 0; r < 4; ++r)
            fin[rf][r] = finished[row0 + 32*wr + 16*rf + lg*4 + r];

#pragma unroll
    for (int cf = 0; cf < 4; ++cf) {
        const int col = col0 + 64*wc + 16*cf + ll;
        const float bv = fcb[col];
#pragma unroll
        for (int rf = 0; rf < 2; ++rf) {
#pragma unroll
            for (int r = 0; r < 4; ++r) {
                const int row = row0 + 32*wr + 16*rf + lg*4 + r;
                const float o = fin[rf][r] ? 0.0f
                    : (accM[rf][cf][r] + accC[rf][cf][r] * INV_SCALE + bv);
                logits[((size_t)row * M_ + t) * V_ + col] = o;
            }
        }
    }
}

// ---------------------------------------------------------------------------
// argmax over the just-written logits row + finalize + next-step x gather/split.
// one block per batch row.
// ---------------------------------------------------------------------------
__global__ __launch_bounds__(256)
void argmax_finalize(const float* __restrict__ logits, const float* __restrict__ emb,
                     int* __restrict__ inputs, int* __restrict__ finished,
                     float* __restrict__ decoded_out, float* __restrict__ mask_out,
                     half_t* __restrict__ xa, half_t* __restrict__ xb, int t)
{
    const int b = blockIdx.x;
    const int tid = threadIdx.x;
    const float* row = logits + ((size_t)b * M_ + t) * V_;

    float bv = -INFINITY; int bi = 0x7fffffff;
    for (int ii = 0; ii < 16; ++ii) {
        const int i4 = tid + 256 * ii;
        if (i4 < V_ / 4) {
            const float4 v = *(const float4*)(row + 4 * i4);
            const float vv[4] = {v.x, v.y, v.z, v.w};
#pragma unroll
            for (int j = 0; j < 4; ++j) {
                const int idx = 4 * i4 + j;
                if (vv[j] > bv || (vv[j] == bv && idx < bi)) { bv = vv[j]; bi = idx; }
            }
        }
    }
    __shared__ float sv[256];
    __shared__ int   si[256];
    sv[tid] = bv; si[tid] = bi;
    __syncthreads();
    for (int s = 128; s > 0; s >>= 1) {
        if (tid < s) {
            const float v2 = sv[tid + s]; const int i2 = si[tid + s];
            if (v2 > sv[tid] || (v2 == sv[tid] && i2 < si[tid])) { sv[tid] = v2; si[tid] = i2; }
        }
        __syncthreads();
    }
    __shared__ int s_tok;
    if (tid == 0) {
        const int fin = finished[b];
        const int dec = si[0];
        decoded_out[b * M_ + t] = fin ? -1.0f : (float)dec;
        mask_out   [b * M_ + t] = fin ? 0.0f : 1.0f;
        int tok;
        if (!fin) { inputs[b] = dec; if (dec == EOS_) finished[b] = 1; tok = dec; }
        else tok = inputs[b];
        s_tok = tok;
    }
    __syncthreads();
    const int tok = s_tok;
    for (int j = tid; j < H_; j += 256) {
        const float v = emb[(size_t)tok * H_ + j];
        half_t a, bb; split_f32(v, a, bb);
        xa[b * H_ + j] = a; xb[b * H_ + j] = bb;
    }
}

// ---------------------------------------------------------------------------
extern "C" void kernel_launch(void* const* d_in, const int* in_sizes, int n_in,
                              void* d_out, int out_size, void* d_ws, size_t ws_size,
                              hipStream_t stream)
{
    const float* sem_f = (const float*)d_in[0];
    const float* emb   = (const float*)d_in[1];
    const float* W_ih0 = (const float*)d_in[2];
    const float* W_hh0 = (const float*)d_in[3];
    const float* b_ih0 = (const float*)d_in[4];
    const float* b_hh0 = (const float*)d_in[5];
    const float* W_ih1 = (const float*)d_in[6];
    const float* W_hh1 = (const float*)d_in[7];
    const float* b_ih1 = (const float*)d_in[8];
    const float* b_hh1 = (const float*)d_in[9];
    const float* fc_W  = (const float*)d_in[10];
    const float* fc_b  = (const float*)d_in[11];

    float* out = (float*)d_out;
    float* decoded_out = out;                                          // [B,M]
    float* logits_out  = out + (size_t)B_ * M_;                        // [B,M,V]
    float* mask_out    = out + (size_t)B_ * M_ + (size_t)B_ * M_ * V_; // [B,M]

    // workspace carve (float-offset units)
    float*  ws  = (float*)d_ws;
    float*  h0  = ws;                               // 131072 f
    float*  h1  = ws + 131072;                      // 131072 f
    float*  PRE = ws + 262144;                      // 786432 f
    half_t* h0a = (half_t*)(ws + 1048576);          // 131072 h
    half_t* h0b = (half_t*)(ws + 1114112);
    half_t* h1a = (half_t*)(ws + 1179648);
    half_t* h1b = (half_t*)(ws + 1245184);
    half_t* xa  = (half_t*)(ws + 1310720);
    half_t* xb  = (half_t*)(ws + 1376256);
    int*    inputs   = (int*)(ws + 1441792);        // 256
    int*    finished = (int*)(ws + 1442048);        // 256

    init_kernel<<<(B_ * H_ + 255) / 256, 256, 0, stream>>>(
        sem_f, emb, h0, h1, h0a, h0b, h1a, h1b, xa, xb, inputs, finished);

    const dim3 gruGrid(24, 8);
    const dim3 fcGrid(125, 4);

    for (int t = 0; t < M_; ++t) {
        gru_gemm_mfma<<<gruGrid, 256, 0, stream>>>(
            xa, xb, h0a, h0b, W_ih0, W_hh0, b_ih0, b_hh0, PRE);
        gate_kernel<<<(B_ * H_) / 256, 256, 0, stream>>>(PRE, h0, h0a, h0b, finished);
        gru_gemm_mfma<<<gruGrid, 256, 0, stream>>>(
            h0a, h0b, h1a, h1b, W_ih1, W_hh1, b_ih1, b_hh1, PRE);
        gate_kernel<<<(B_ * H_) / 256, 256, 0, stream>>>(PRE, h1, h1a, h1b, finished);
        fc_gemm_mfma<<<fcGrid, 256, 0, stream>>>(
            h1a, h1b, fc_W, fc_b, finished, logits_out, t);
        argmax_finalize<<<B_, 256, 0, stream>>>(
            logits_out, emb, inputs, finished, decoded_out, mask_out, xa, xb, t);
    }
}

// Round 3
// 2978.749 us; speedup vs baseline: 1.6232x; 1.0336x over previous
//
#include <hip/hip_runtime.h>
#include <math.h>

#define B_   256
#define H_   512
#define V_   16000
#define M_   32
#define SOS_ 1
#define EOS_ 2
#define INV_SCALE (1.0f/2048.0f)

typedef _Float16 half_t;
typedef _Float16 f16x8 __attribute__((ext_vector_type(8)));
typedef _Float16 f16x4 __attribute__((ext_vector_type(4)));
typedef float    f32x4 __attribute__((ext_vector_type(4)));

__device__ __forceinline__ void split_f32(float x, half_t& a, half_t& b) {
    a = (half_t)x;
    b = (half_t)((x - (float)a) * 2048.0f);
}

// ---------------------------------------------------------------------------
// one-time weight split: fp32 -> fp16 hi/lo planes (persisted in ws for the call)
// ---------------------------------------------------------------------------
__global__ __launch_bounds__(256)
void split_weights(const float* __restrict__ src, half_t* __restrict__ hi,
                   half_t* __restrict__ lo, int n4)
{
    const int i = blockIdx.x * 256 + threadIdx.x;
    if (i >= n4) return;
    const float4 v = ((const float4*)src)[i];
    f16x4 a, b;
    half_t t0, t1;
    split_f32(v.x, t0, t1); a[0] = t0; b[0] = t1;
    split_f32(v.y, t0, t1); a[1] = t0; b[1] = t1;
    split_f32(v.z, t0, t1); a[2] = t0; b[2] = t1;
    split_f32(v.w, t0, t1); a[3] = t0; b[3] = t1;
    ((f16x4*)hi)[i] = a;
    ((f16x4*)lo)[i] = b;
}

// ---------------------------------------------------------------------------
// init: h0 = h1 = sem_f (+ splits); x = emb[SOS] split; inputs; finished
// ---------------------------------------------------------------------------
__global__ __launch_bounds__(256)
void init_kernel(const float* __restrict__ sem_f, const float* __restrict__ emb,
                 float* __restrict__ h0, float* __restrict__ h1,
                 half_t* __restrict__ h0a, half_t* __restrict__ h0b,
                 half_t* __restrict__ h1a, half_t* __restrict__ h1b,
                 half_t* __restrict__ xa,  half_t* __restrict__ xb,
                 int* __restrict__ inputs, int* __restrict__ finished)
{
    const int i = blockIdx.x * 256 + threadIdx.x;
    if (i < B_ * H_) {
        const float v = sem_f[i];
        h0[i] = v; h1[i] = v;
        half_t a, b; split_f32(v, a, b);
        h0a[i] = a; h0b[i] = b;
        h1a[i] = a; h1b[i] = b;
        const int j = i & (H_ - 1);
        const float xv = emb[SOS_ * H_ + j];
        half_t c, d; split_f32(xv, c, d);
        xa[i] = c; xb[i] = d;
    }
    if (i < B_) { inputs[i] = SOS_; finished[i] = 0; }
}

// ---------------------------------------------------------------------------
// GRU pre-activation GEMM (fp16x2 3-pass MFMA), W pre-split.
// grid (24, 8): ct = 128-col tile over 3072 (ct<12 -> ih), rt = 32-row tile.
// ---------------------------------------------------------------------------
__global__ __launch_bounds__(256)
void gru_gemm_mfma(const half_t* __restrict__ Aia, const half_t* __restrict__ Aib,
                   const half_t* __restrict__ Aha, const half_t* __restrict__ Ahb,
                   const half_t* __restrict__ Wia, const half_t* __restrict__ Wib,
                   const half_t* __restrict__ Wha, const half_t* __restrict__ Whb,
                   const float* __restrict__ b_ih, const float* __restrict__ b_hh,
                   float* __restrict__ PRE)
{
    const int ct = blockIdx.x;            // 0..23
    const int rt = blockIdx.y;            // 0..7
    const bool is_ih = (ct < 12);
    const int wrow0 = (is_ih ? ct : ct - 12) * 128;
    const int row0  = rt * 32;
    const float*  bias = is_ih ? b_ih : b_hh;
    const half_t* Aa   = is_ih ? Aia : Aha;
    const half_t* Ab   = is_ih ? Aib : Ahb;
    const half_t* W0   = is_ih ? Wia : Wha;
    const half_t* W1   = is_ih ? Wib : Whb;

    __shared__ half_t W0s[128][40];
    __shared__ half_t W1s[128][40];

    const int tid  = threadIdx.x;
    const int w    = tid >> 6;
    const int lane = tid & 63;
    const int ll   = lane & 15;
    const int lg   = lane >> 4;

    const int sc = tid >> 1;
    const int sk = (tid & 1) * 16;
    const half_t* wp0 = W0 + (size_t)(wrow0 + sc) * H_ + sk;
    const half_t* wp1 = W1 + (size_t)(wrow0 + sc) * H_ + sk;

    f32x4 accM[2][2] = {};
    f32x4 accC[2][2] = {};

    for (int k0 = 0; k0 < H_; k0 += 32) {
        const f16x8 s0 = *(const f16x8*)(wp0 + k0);
        const f16x8 s1 = *(const f16x8*)(wp0 + k0 + 8);
        const f16x8 s2 = *(const f16x8*)(wp1 + k0);
        const f16x8 s3 = *(const f16x8*)(wp1 + k0 + 8);
        __syncthreads();
        *(f16x8*)&W0s[sc][sk]     = s0;
        *(f16x8*)&W0s[sc][sk + 8] = s1;
        *(f16x8*)&W1s[sc][sk]     = s2;
        *(f16x8*)&W1s[sc][sk + 8] = s3;
        __syncthreads();

        f16x8 a0[2], a1[2];
#pragma unroll
        for (int rf = 0; rf < 2; ++rf) {
            const size_t off = ((size_t)(row0 + 16*rf + ll) << 9) + k0 + (lg << 3);
            a0[rf] = *(const f16x8*)(Aa + off);
            a1[rf] = *(const f16x8*)(Ab + off);
        }
#pragma unroll
        for (int cf = 0; cf < 2; ++cf) {
            const int c = 32*w + 16*cf + ll;
            const f16x8 b0 = *(const f16x8*)&W0s[c][lg << 3];
            const f16x8 b1 = *(const f16x8*)&W1s[c][lg << 3];
#pragma unroll
            for (int rf = 0; rf < 2; ++rf) {
                accM[rf][cf] = __builtin_amdgcn_mfma_f32_16x16x32_f16(a0[rf], b0, accM[rf][cf], 0,0,0);
                accC[rf][cf] = __builtin_amdgcn_mfma_f32_16x16x32_f16(a0[rf], b1, accC[rf][cf], 0,0,0);
                accC[rf][cf] = __builtin_amdgcn_mfma_f32_16x16x32_f16(a1[rf], b0, accC[rf][cf], 0,0,0);
            }
        }
    }

#pragma unroll
    for (int cf = 0; cf < 2; ++cf) {
        const int cl = 32*w + 16*cf + ll;
        const float bv = bias[wrow0 + cl];
        const int c = ct * 128 + cl;
#pragma unroll
        for (int rf = 0; rf < 2; ++rf) {
#pragma unroll
            for (int r = 0; r < 4; ++r) {
                const int row = row0 + 16*rf + lg*4 + r;
                PRE[(size_t)row * 3072 + c] = accM[rf][cf][r] + accC[rf][cf][r] * INV_SCALE + bv;
            }
        }
    }
}

// ---------------------------------------------------------------------------
// GRU gate math; in-place h update with freeze + fp16x2 split emit.
// ---------------------------------------------------------------------------
__global__ __launch_bounds__(256)
void gate_kernel(const float* __restrict__ PRE,
                 float* __restrict__ h,
                 half_t* __restrict__ ha, half_t* __restrict__ hb,
                 const int* __restrict__ finished)
{
    const int idx = blockIdx.x * 256 + threadIdx.x;
    const int b = idx >> 9;
    const int j = idx & 511;
    if (finished[b]) return;
    const float* p = PRE + (size_t)b * 3072;
    const float ir = p[j],        iz = p[512 + j],  in_ = p[1024 + j];
    const float hr = p[1536 + j], hz = p[2048 + j], hn  = p[2560 + j];
    const float r = 1.0f / (1.0f + expf(-(ir + hr)));
    const float z = 1.0f / (1.0f + expf(-(iz + hz)));
    const float n = tanhf(in_ + r * hn);
    const float hv = (1.0f - z) * n + z * h[idx];
    h[idx] = hv;
    half_t a, bb; split_f32(hv, a, bb);
    ha[idx] = a; hb[idx] = bb;
}

// ---------------------------------------------------------------------------
// FC GEMM (fp16x2 3-pass MFMA, W pre-split) + logits store + argmax partials.
// grid (125, 4): 128-col x 64-row tiles; waves 2x2; wave = 32 rows x 64 cols.
// ---------------------------------------------------------------------------
__global__ __launch_bounds__(256)
void fc_gemm_mfma(const half_t* __restrict__ Aa, const half_t* __restrict__ Ab,
                  const half_t* __restrict__ W0, const half_t* __restrict__ W1,
                  const float* __restrict__ fcb,
                  const int* __restrict__ finished,
                  float* __restrict__ logits,
                  float* __restrict__ pmax, int* __restrict__ pidx, int t)
{
    const int ct = blockIdx.x;            // 0..124
    const int rt = blockIdx.y;            // 0..3
    const int col0 = ct * 128;
    const int row0 = rt * 64;

    __shared__ half_t W0s[128][40];
    __shared__ half_t W1s[128][40];
    __shared__ float  pmS[64][2];
    __shared__ int    piS[64][2];

    const int tid  = threadIdx.x;
    const int wv   = tid >> 6;
    const int wr   = wv >> 1, wc = wv & 1;
    const int lane = tid & 63;
    const int ll   = lane & 15, lg = lane >> 4;

    const int sc = tid >> 1;
    const int sk = (tid & 1) * 16;
    const half_t* wp0 = W0 + (size_t)(col0 + sc) * H_ + sk;
    const half_t* wp1 = W1 + (size_t)(col0 + sc) * H_ + sk;

    f32x4 accM[2][4] = {};
    f32x4 accC[2][4] = {};

    for (int k0 = 0; k0 < H_; k0 += 32) {
        const f16x8 s0 = *(const f16x8*)(wp0 + k0);
        const f16x8 s1 = *(const f16x8*)(wp0 + k0 + 8);
        const f16x8 s2 = *(const f16x8*)(wp1 + k0);
        const f16x8 s3 = *(const f16x8*)(wp1 + k0 + 8);
        __syncthreads();
        *(f16x8*)&W0s[sc][sk]     = s0;
        *(f16x8*)&W0s[sc][sk + 8] = s1;
        *(f16x8*)&W1s[sc][sk]     = s2;
        *(f16x8*)&W1s[sc][sk + 8] = s3;
        __syncthreads();

        f16x8 a0[2], a1[2];
#pragma unroll
        for (int rf = 0; rf < 2; ++rf) {
            const size_t off = ((size_t)(row0 + 32*wr + 16*rf + ll) << 9) + k0 + (lg << 3);
            a0[rf] = *(const f16x8*)(Aa + off);
            a1[rf] = *(const f16x8*)(Ab + off);
        }
#pragma unroll
        for (int cf = 0; cf < 4; ++cf) {
            const int c = 64*wc + 16*cf + ll;
            const f16x8 b0 = *(const f16x8*)&W0s[c][lg << 3];
            const f16x8 b1 = *(const f16x8*)&W1s[c][lg << 3];
#pragma unroll
            for (int rf = 0; rf < 2; ++rf) {
                accM[rf][cf] = __builtin_amdgcn_mfma_f32_16x16x32_f16(a0[rf], b0, accM[rf][cf], 0,0,0);
                accC[rf][cf] = __builtin_amdgcn_mfma_f32_16x16x32_f16(a0[rf], b1, accC[rf][cf], 0,0,0);
                accC[rf][cf] = __builtin_amdgcn_mfma_f32_16x16x32_f16(a1[rf], b0, accC[rf][cf], 0,0,0);
            }
        }
    }

    int fin[2][4];
#pragma unroll
    for (int rf = 0; rf < 2; ++rf)
#pragma unroll
        for (int r = 0; r < 4; ++r)
            fin[rf][r] = finished[row0 + 32*wr + 16*rf + lg*4 + r];

    float bvv[2][4];
    int   bii[2][4];
#pragma unroll
    for (int rf = 0; rf < 2; ++rf)
#pragma unroll
        for (int r = 0; r < 4; ++r) { bvv[rf][r] = -INFINITY; bii[rf][r] = 0x7fffffff; }

#pragma unroll
    for (int cf = 0; cf < 4; ++cf) {
        const int col = col0 + 64*wc + 16*cf + ll;
        const float bv = fcb[col];
#pragma unroll
        for (int rf = 0; rf < 2; ++rf) {
#pragma unroll
            for (int r = 0; r < 4; ++r) {
                const int row = row0 + 32*wr + 16*rf + lg*4 + r;
                const float raw = accM[rf][cf][r] + accC[rf][cf][r] * INV_SCALE + bv;
                logits[((size_t)row * M_ + t) * V_ + col] = fin[rf][r] ? 0.0f : raw;
                if (raw > bvv[rf][r]) { bvv[rf][r] = raw; bii[rf][r] = col; } // cf asc => first-max
            }
        }
    }

    // reduce argmax over the 16 ll-lanes (cols) per row
#pragma unroll
    for (int rf = 0; rf < 2; ++rf) {
#pragma unroll
        for (int r = 0; r < 4; ++r) {
            float v = bvv[rf][r]; int ix = bii[rf][r];
#pragma unroll
            for (int m = 1; m < 16; m <<= 1) {
                const float ov = __shfl_xor(v, m);
                const int   oi = __shfl_xor(ix, m);
                if (ov > v || (ov == v && oi < ix)) { v = ov; ix = oi; }
            }
            if (ll == 0) {
                const int lr = 32*wr + 16*rf + lg*4 + r;
                pmS[lr][wc] = v; piS[lr][wc] = ix;
            }
        }
    }
    __syncthreads();
    if (tid < 64) {
        float v = pmS[tid][0]; int ix = piS[tid][0];
        const float v2 = pmS[tid][1]; const int i2 = piS[tid][1];
        if (v2 > v || (v2 == v && i2 < ix)) { v = v2; ix = i2; }
        pmax[(row0 + tid) * 128 + ct] = v;
        pidx[(row0 + tid) * 128 + ct] = ix;
    }
}

// ---------------------------------------------------------------------------
// finalize: reduce 125 partials per row, write decoded/mask, update state,
// gather+split next x.
// ---------------------------------------------------------------------------
__global__ __launch_bounds__(128)
void finalize_kernel(const float* __restrict__ pmax, const int* __restrict__ pidx,
                     const float* __restrict__ emb,
                     int* __restrict__ inputs, int* __restrict__ finished,
                     float* __restrict__ decoded_out, float* __restrict__ mask_out,
                     half_t* __restrict__ xa, half_t* __restrict__ xb, int t)
{
    const int b = blockIdx.x;
    const int tid = threadIdx.x;
    __shared__ float sv[128];
    __shared__ int   si[128];
    float v = -INFINITY; int ix = 0x7fffffff;
    if (tid < 125) { v = pmax[b * 128 + tid]; ix = pidx[b * 128 + tid]; }
    sv[tid] = v; si[tid] = ix;
    __syncthreads();
    for (int s = 64; s > 0; s >>= 1) {
        if (tid < s) {
            const float v2 = sv[tid + s]; const int i2 = si[tid + s];
            if (v2 > sv[tid] || (v2 == sv[tid] && i2 < si[tid])) { sv[tid] = v2; si[tid] = i2; }
        }
        __syncthreads();
    }
    __shared__ int s_tok;
    if (tid == 0) {
        const int fin = finished[b];
        const int dec = si[0];
        decoded_out[b * M_ + t] = fin ? -1.0f : (float)dec;
        mask_out   [b * M_ + t] = fin ? 0.0f : 1.0f;
        int tok;
        if (!fin) { inputs[b] = dec; if (dec == EOS_) finished[b] = 1; tok = dec; }
        else tok = inputs[b];
        s_tok = tok;
    }
    __syncthreads();
    const int tok = s_tok;
    for (int j = tid; j < H_; j += 128) {
        const float v2 = emb[(size_t)tok * H_ + j];
        half_t a, bb; split_f32(v2, a, bb);
        xa[b * H_ + j] = a; xb[b * H_ + j] = bb;
    }
}

// ---------------------------------------------------------------------------
extern "C" void kernel_launch(void* const* d_in, const int* in_sizes, int n_in,
                              void* d_out, int out_size, void* d_ws, size_t ws_size,
                              hipStream_t stream)
{
    const float* sem_f = (const float*)d_in[0];
    const float* emb   = (const float*)d_in[1];
    const float* W_ih0 = (const float*)d_in[2];
    const float* W_hh0 = (const float*)d_in[3];
    const float* b_ih0 = (const float*)d_in[4];
    const float* b_hh0 = (const float*)d_in[5];
    const float* W_ih1 = (const float*)d_in[6];
    const float* W_hh1 = (const float*)d_in[7];
    const float* b_ih1 = (const float*)d_in[8];
    const float* b_hh1 = (const float*)d_in[9];
    const float* fc_W  = (const float*)d_in[10];
    const float* fc_b  = (const float*)d_in[11];

    float* out = (float*)d_out;
    float* decoded_out = out;
    float* logits_out  = out + (size_t)B_ * M_;
    float* mask_out    = out + (size_t)B_ * M_ + (size_t)B_ * M_ * V_;

    // workspace carve (float units)
    float*  ws  = (float*)d_ws;
    float*  PRE = ws;                                // 786432
    float*  h0  = ws + 786432;                       // 131072
    float*  h1  = ws + 917504;                       // 131072
    half_t* h0a = (half_t*)(ws + 1048576);           // 131072 h (65536 f)
    half_t* h0b = (half_t*)(ws + 1114112);
    half_t* h1a = (half_t*)(ws + 1179648);
    half_t* h1b = (half_t*)(ws + 1245184);
    half_t* xa  = (half_t*)(ws + 1310720);
    half_t* xb  = (half_t*)(ws + 1376256);
    float*  pmax = ws + 1441792;                     // 256*128
    int*    pidx = (int*)(ws + 1474560);             // 256*128
    int*    inputs   = (int*)(ws + 1507328);
    int*    finished = (int*)(ws + 1507584);
    half_t* wi0a = (half_t*)(ws + 1507840);          // each 1536*512 h = 393216 f
    half_t* wi0b = (half_t*)(ws + 1901056);
    half_t* wh0a = (half_t*)(ws + 2294272);
    half_t* wh0b = (half_t*)(ws + 2687488);
    half_t* wi1a = (half_t*)(ws + 3080704);
    half_t* wi1b = (half_t*)(ws + 3473920);
    half_t* wh1a = (half_t*)(ws + 3867136);
    half_t* wh1b = (half_t*)(ws + 4260352);
    half_t* fca  = (half_t*)(ws + 4653568);          // 16000*512 h = 4096000 f
    half_t* fcbp = (half_t*)(ws + 8749568);          // low plane
    // total: 12,845,568 floats = 51.4 MB

    const int nGru4 = (1536 * 512) / 4;
    const int nFc4  = (V_ * H_) / 4;
    split_weights<<<(nGru4 + 255) / 256, 256, 0, stream>>>(W_ih0, wi0a, wi0b, nGru4);
    split_weights<<<(nGru4 + 255) / 256, 256, 0, stream>>>(W_hh0, wh0a, wh0b, nGru4);
    split_weights<<<(nGru4 + 255) / 256, 256, 0, stream>>>(W_ih1, wi1a, wi1b, nGru4);
    split_weights<<<(nGru4 + 255) / 256, 256, 0, stream>>>(W_hh1, wh1a, wh1b, nGru4);
    split_weights<<<(nFc4 + 255) / 256, 256, 0, stream>>>(fc_W, fca, fcbp, nFc4);

    init_kernel<<<(B_ * H_ + 255) / 256, 256, 0, stream>>>(
        sem_f, emb, h0, h1, h0a, h0b, h1a, h1b, xa, xb, inputs, finished);

    const dim3 gruGrid(24, 8);
    const dim3 fcGrid(125, 4);

    for (int t = 0; t < M_; ++t) {
        gru_gemm_mfma<<<gruGrid, 256, 0, stream>>>(
            xa, xb, h0a, h0b, wi0a, wi0b, wh0a, wh0b, b_ih0, b_hh0, PRE);
        gate_kernel<<<(B_ * H_) / 256, 256, 0, stream>>>(PRE, h0, h0a, h0b, finished);
        gru_gemm_mfma<<<gruGrid, 256, 0, stream>>>(
            h0a, h0b, h1a, h1b, wi1a, wi1b, wh1a, wh1b, b_ih1, b_hh1, PRE);
        gate_kernel<<<(B_ * H_) / 256, 256, 0, stream>>>(PRE, h1, h1a, h1b, finished);
        fc_gemm_mfma<<<fcGrid, 256, 0, stream>>>(
            h1a, h1b, fca, fcbp, fc_b, finished, logits_out, pmax, pidx, t);
        finalize_kernel<<<B_, 128, 0, stream>>>(
            pmax, pidx, emb, inputs, finished, decoded_out, mask_out, xa, xb, t);
    }
}